// Round 2
// baseline (380.580 us; speedup 1.0000x reference)
//
#include <hip/hip_runtime.h>
#include <hip/hip_bf16.h>
#include <stdint.h>

#define Bdim 8
#define Nseq 1024
#define Cdim 768
#define Hn 12
#define HD 64
#define EPSf 1e-6f

typedef __bf16 bf16;
typedef __bf16 bf16x8 __attribute__((ext_vector_type(8)));
typedef float f32x4 __attribute__((ext_vector_type(4)));

static __device__ __forceinline__ void gload_lds16(const bf16* g, bf16* lds) {
  __builtin_amdgcn_global_load_lds(
      (const __attribute__((address_space(1))) uint32_t*)g,
      (__attribute__((address_space(3))) uint32_t*)lds, 16, 0, 0);
}

// ---------------- fp32 -> bf16 convert (8 elems/thread, sizes are multiples of 2048)
__global__ __launch_bounds__(256) void cvt_f32_bf16(const float* __restrict__ src,
                                                    bf16* __restrict__ dst, int n) {
  const int i = (blockIdx.x * 256 + threadIdx.x) * 8;
  if (i >= n) return;
  float4 a = *(const float4*)(src + i);
  float4 b = *(const float4*)(src + i + 4);
  bf16x8 o;
  o[0] = (bf16)a.x; o[1] = (bf16)a.y; o[2] = (bf16)a.z; o[3] = (bf16)a.w;
  o[4] = (bf16)b.x; o[5] = (bf16)b.y; o[6] = (bf16)b.z; o[7] = (bf16)b.w;
  *(bf16x8*)(dst + i) = o;
}

// ---------------- QKV GEMM: X(8192x768) @ Wqkv^T(768x2304) -> Q,K (B,H,N,hd) + Vt (B,H,hd,N)
__global__ __launch_bounds__(256) void gemm_qkv(
    const bf16* __restrict__ X, const bf16* __restrict__ W,
    bf16* __restrict__ Qb, bf16* __restrict__ Kb, bf16* __restrict__ Vt) {
  __shared__ __align__(16) bf16 As[128 * 32];
  __shared__ __align__(16) bf16 Bs[128 * 32];
  const int t = threadIdx.x;
  const int lane = t & 63;
  const int w = t >> 6;
  const int l15 = lane & 15, quad = lane >> 4;
  const int wm = w & 1, wn = w >> 1;
  const int mbase = blockIdx.y * 128;
  const int nbase = blockIdx.x * 128;
  constexpr int K = Cdim;

  const int srow = t >> 2;
  const int scol = (t & 3) * 8;
  const bf16* Ag = X + (size_t)(mbase + srow) * K + scol;
  const bf16* Bg = W + (size_t)(nbase + srow) * K + scol;
  bf16* AsT = As + t * 8;  // lane0 of each wave supplies the wave-uniform LDS base
  bf16* BsT = Bs + t * 8;

  f32x4 acc[4][4] = {};

  for (int kt = 0; kt < K; kt += 32) {
    gload_lds16(Ag + kt, AsT);
    gload_lds16(Ag + (size_t)64 * K + kt, AsT + 2048);
    gload_lds16(Bg + kt, BsT);
    gload_lds16(Bg + (size_t)64 * K + kt, BsT + 2048);
    __syncthreads();
    bf16x8 a[4], b[4];
#pragma unroll
    for (int mt = 0; mt < 4; mt++)
      a[mt] = *(const bf16x8*)(As + (wm * 64 + mt * 16 + l15) * 32 + quad * 8);
#pragma unroll
    for (int nt = 0; nt < 4; nt++)
      b[nt] = *(const bf16x8*)(Bs + (wn * 64 + nt * 16 + l15) * 32 + quad * 8);
#pragma unroll
    for (int mt = 0; mt < 4; mt++)
#pragma unroll
      for (int nt = 0; nt < 4; nt++)
        acc[mt][nt] = __builtin_amdgcn_mfma_f32_16x16x32_bf16(a[mt], b[nt], acc[mt][nt], 0, 0, 0);
    __syncthreads();
  }

  const int s = nbase / Cdim;  // uniform per block (768 % 128 == 0)
  const int jbase = (nbase % Cdim) + wn * 64;
#pragma unroll
  for (int nt = 0; nt < 4; nt++) {
    const int jj = jbase + nt * 16 + l15;
    const int h = jj >> 6, d = jj & 63;
#pragma unroll
    for (int mt = 0; mt < 4; mt++) {
#pragma unroll
      for (int r = 0; r < 4; r++) {
        const int m = mbase + wm * 64 + mt * 16 + quad * 4 + r;
        const int b_ = m >> 10, n = m & 1023;
        const bf16 v = (bf16)acc[mt][nt][r];
        const size_t bh = (size_t)b_ * Hn + h;
        if (s == 0)      Qb[(bh * Nseq + n) * HD + d] = v;
        else if (s == 1) Kb[(bh * Nseq + n) * HD + d] = v;
        else             Vt[(bh * HD + d) * Nseq + n] = v;  // transposed V
      }
    }
  }
}

// ---------------- column sums of V per (b,h,d): one wave per Vt row
__global__ __launch_bounds__(256) void colsum_v(const bf16* __restrict__ Vt,
                                                float* __restrict__ CS) {
  const int row = blockIdx.x * 4 + (threadIdx.x >> 6);
  const int lane = threadIdx.x & 63;
  const bf16x8* p = (const bf16x8*)(Vt + (size_t)row * Nseq + lane * 16);
  bf16x8 v0 = p[0], v1 = p[1];
  float s = 0.f;
#pragma unroll
  for (int i = 0; i < 8; i++) s += (float)v0[i] + (float)v1[i];
#pragma unroll
  for (int off = 1; off < 64; off <<= 1) s += __shfl_xor(s, off);
  if (lane == 0) CS[row] = s;
}

// ---------------- fused flash attention with policy softmax
// one wave per 16-query tile; 4 waves/block; key tiles of 32
__global__ __launch_bounds__(256) void attn_fused(
    const bf16* __restrict__ Qb, const bf16* __restrict__ Kb, const bf16* __restrict__ Vt,
    const float* __restrict__ pol, const float* __restrict__ CS, bf16* __restrict__ O) {
  __shared__ __align__(16) bf16 Pbuf[4][16 * 32];
  const int t = threadIdx.x, w = t >> 6, lane = t & 63;
  const int l15 = lane & 15, quad = lane >> 4;
  const int qt = blockIdx.x & 15, bh = blockIdx.x >> 4;
  const int b_ = bh / Hn, h = bh % Hn;
  const int qbase = qt * 64 + w * 16;
  const bf16* Qp = Qb + (size_t)bh * Nseq * HD;
  const bf16* Kp = Kb + (size_t)bh * Nseq * HD;
  const bf16* Vp = Vt + (size_t)bh * HD * Nseq;
  const float* polb = pol + (size_t)b_ * Nseq;

  // Q fragments (A-layout: A[m=l15][k=quad*8+j]), loaded once
  const bf16x8 aq0 = *(const bf16x8*)(Qp + (qbase + l15) * HD + quad * 8);
  const bf16x8 aq1 = *(const bf16x8*)(Qp + (qbase + l15) * HD + 32 + quad * 8);

  const int qrow = qbase + quad * 4;
  float polq[4];
#pragma unroll
  for (int r = 0; r < 4; r++) polq[r] = polb[qrow + r];

  float mrow[4], lrow[4];
  f32x4 oacc[4] = {};
#pragma unroll
  for (int r = 0; r < 4; r++) { mrow[r] = -1e30f; lrow[r] = 0.f; }

  bf16* Pw = &Pbuf[w][0];
  const float scale = 0.125f;  // hd^-0.5

  for (int kt = 0; kt < Nseq; kt += 32) {
    f32x4 S0 = {}, S1 = {};
    {
      bf16x8 bk0 = *(const bf16x8*)(Kp + (kt + l15) * HD + quad * 8);
      bf16x8 bk1 = *(const bf16x8*)(Kp + (kt + l15) * HD + 32 + quad * 8);
      S0 = __builtin_amdgcn_mfma_f32_16x16x32_bf16(aq0, bk0, S0, 0, 0, 0);
      S0 = __builtin_amdgcn_mfma_f32_16x16x32_bf16(aq1, bk1, S0, 0, 0, 0);
      bf16x8 bk2 = *(const bf16x8*)(Kp + (kt + 16 + l15) * HD + quad * 8);
      bf16x8 bk3 = *(const bf16x8*)(Kp + (kt + 16 + l15) * HD + 32 + quad * 8);
      S1 = __builtin_amdgcn_mfma_f32_16x16x32_bf16(aq0, bk2, S1, 0, 0, 0);
      S1 = __builtin_amdgcn_mfma_f32_16x16x32_bf16(aq1, bk3, S1, 0, 0, 0);
    }
    S0 *= scale;
    S1 *= scale;
    const float polk0 = polb[kt + l15];
    const float polk1 = polb[kt + 16 + l15];
#pragma unroll
    for (int r = 0; r < 4; r++) {
      // tile row-max across the 16 lanes of this quad-group (unmasked, as reference)
      float v = fmaxf(S0[r], S1[r]);
      v = fmaxf(v, __shfl_xor(v, 1));
      v = fmaxf(v, __shfl_xor(v, 2));
      v = fmaxf(v, __shfl_xor(v, 4));
      v = fmaxf(v, __shfl_xor(v, 8));
      const float mnew = fmaxf(mrow[r], v);
      const float alpha = __expf(mrow[r] - mnew);  // 0 on first tile (underflow)
      mrow[r] = mnew;
      const int q = qrow + r;
      const float msk0 = polk0 * polq[r] + (1.f - polk0) * ((q == kt + l15) ? 1.f : 0.f);
      const float msk1 = polk1 * polq[r] + (1.f - polk1) * ((q == kt + 16 + l15) ? 1.f : 0.f);
      const float p0 = __expf(S0[r] - mnew) * msk0;
      const float p1 = __expf(S1[r] - mnew) * msk1;
      lrow[r] = lrow[r] * alpha + p0 + p1;  // per-lane partial over keys == l15 (mod 16)
#pragma unroll
      for (int c = 0; c < 4; c++) oacc[c][r] *= alpha;
      Pw[(quad * 4 + r) * 32 + l15] = (bf16)p0;
      Pw[(quad * 4 + r) * 32 + 16 + l15] = (bf16)p1;
    }
    asm volatile("s_waitcnt lgkmcnt(0)" ::: "memory");
    // P re-read in A-layout; V fragments from transposed Vt are contiguous 16B
    const bf16x8 ap = *(const bf16x8*)(Pw + l15 * 32 + quad * 8);
#pragma unroll
    for (int c = 0; c < 4; c++) {
      bf16x8 bv = *(const bf16x8*)(Vp + (c * 16 + l15) * Nseq + kt + quad * 8);
      oacc[c] = __builtin_amdgcn_mfma_f32_16x16x32_bf16(ap, bv, oacc[c], 0, 0, 0);
    }
  }

  // reduce partial row sums across the 16 lanes of the quad-group
#pragma unroll
  for (int r = 0; r < 4; r++) {
    float v = lrow[r];
    v += __shfl_xor(v, 1);
    v += __shfl_xor(v, 2);
    v += __shfl_xor(v, 4);
    v += __shfl_xor(v, 8);
    lrow[r] = v + EPSf;
  }
  const float epsN = EPSf / (float)Nseq;
  const float* CSp = CS + (size_t)bh * HD;
#pragma unroll
  for (int c = 0; c < 4; c++) {
    const float cs = CSp[c * 16 + l15] * epsN;
#pragma unroll
    for (int r = 0; r < 4; r++) {
      const float val = (oacc[c][r] + cs) / lrow[r];
      O[((size_t)b_ * Nseq + (qrow + r)) * Cdim + h * 64 + c * 16 + l15] = (bf16)val;
    }
  }
}

// ---------------- proj GEMM: O(8192x768) @ Wproj^T(768x768) + bias -> out (fp32)
__global__ __launch_bounds__(256) void gemm_proj(
    const bf16* __restrict__ A_, const bf16* __restrict__ W,
    const float* __restrict__ bias, float* __restrict__ out) {
  __shared__ __align__(16) bf16 As[128 * 32];
  __shared__ __align__(16) bf16 Bs[128 * 32];
  const int t = threadIdx.x;
  const int lane = t & 63;
  const int w = t >> 6;
  const int l15 = lane & 15, quad = lane >> 4;
  const int wm = w & 1, wn = w >> 1;
  const int mbase = blockIdx.y * 128;
  const int nbase = blockIdx.x * 128;
  constexpr int K = Cdim;

  const int srow = t >> 2;
  const int scol = (t & 3) * 8;
  const bf16* Ag = A_ + (size_t)(mbase + srow) * K + scol;
  const bf16* Bg = W + (size_t)(nbase + srow) * K + scol;
  bf16* AsT = As + t * 8;
  bf16* BsT = Bs + t * 8;

  f32x4 acc[4][4] = {};

  for (int kt = 0; kt < K; kt += 32) {
    gload_lds16(Ag + kt, AsT);
    gload_lds16(Ag + (size_t)64 * K + kt, AsT + 2048);
    gload_lds16(Bg + kt, BsT);
    gload_lds16(Bg + (size_t)64 * K + kt, BsT + 2048);
    __syncthreads();
    bf16x8 a[4], b[4];
#pragma unroll
    for (int mt = 0; mt < 4; mt++)
      a[mt] = *(const bf16x8*)(As + (wm * 64 + mt * 16 + l15) * 32 + quad * 8);
#pragma unroll
    for (int nt = 0; nt < 4; nt++)
      b[nt] = *(const bf16x8*)(Bs + (wn * 64 + nt * 16 + l15) * 32 + quad * 8);
#pragma unroll
    for (int mt = 0; mt < 4; mt++)
#pragma unroll
      for (int nt = 0; nt < 4; nt++)
        acc[mt][nt] = __builtin_amdgcn_mfma_f32_16x16x32_bf16(a[mt], b[nt], acc[mt][nt], 0, 0, 0);
    __syncthreads();
  }

#pragma unroll
  for (int nt = 0; nt < 4; nt++) {
    const int j = nbase + wn * 64 + nt * 16 + l15;
    const float bj = bias[j];
#pragma unroll
    for (int mt = 0; mt < 4; mt++)
#pragma unroll
      for (int r = 0; r < 4; r++) {
        const int m = mbase + wm * 64 + mt * 16 + quad * 4 + r;
        out[(size_t)m * Cdim + j] = acc[mt][nt][r] + bj;
      }
  }
}

extern "C" void kernel_launch(void* const* d_in, const int* in_sizes, int n_in,
                              void* d_out, int out_size, void* d_ws, size_t ws_size,
                              hipStream_t stream) {
  const float* x = (const float*)d_in[0];
  const float* pol = (const float*)d_in[1];
  const float* Wqkv = (const float*)d_in[2];
  const float* Wproj = (const float*)d_in[3];
  const float* bproj = (const float*)d_in[4];
  float* out = (float*)d_out;
  char* ws = (char*)d_ws;

  const size_t SZ = (size_t)Bdim * Hn * Nseq * HD * sizeof(bf16);  // 12.58 MB
  bf16* Qb = (bf16*)(ws);
  bf16* Kb = (bf16*)(ws + SZ);
  bf16* Vt = (bf16*)(ws + 2 * SZ);
  bf16* O  = (bf16*)(ws + 3 * SZ);
  float* CS = (float*)(ws + 4 * SZ);            // B*H*HD fp32 (24 KB)
  bf16* Xb = (bf16*)(ws + 4 * SZ + 32 * 1024);  // 12.58 MB
  bf16* Wqkvb = Xb + (size_t)Bdim * Nseq * Cdim;         // 3.54 MB
  bf16* Wprojb = Wqkvb + (size_t)3 * Cdim * Cdim;        // 1.18 MB

  const int nx = Bdim * Nseq * Cdim;       // 6291456
  const int nwq = 3 * Cdim * Cdim;         // 1769472
  const int nwp = Cdim * Cdim;             // 589824
  cvt_f32_bf16<<<nx / 2048, 256, 0, stream>>>(x, Xb, nx);
  cvt_f32_bf16<<<nwq / 2048, 256, 0, stream>>>(Wqkv, Wqkvb, nwq);
  cvt_f32_bf16<<<nwp / 2048, 256, 0, stream>>>(Wproj, Wprojb, nwp);

  gemm_qkv<<<dim3(3 * Cdim / 128, (Bdim * Nseq) / 128), 256, 0, stream>>>(Xb, Wqkvb, Qb, Kb, Vt);
  colsum_v<<<(Bdim * Hn * HD) / 4, 256, 0, stream>>>(Vt, CS);
  attn_fused<<<Bdim * Hn * (Nseq / 64), 256, 0, stream>>>(Qb, Kb, Vt, pol, CS, O);
  gemm_proj<<<dim3(Cdim / 128, (Bdim * Nseq) / 128), 256, 0, stream>>>(O, Wprojb, bproj, out);
}

// Round 3
// 265.083 us; speedup vs baseline: 1.4357x; 1.4357x over previous
//
#include <hip/hip_runtime.h>
#include <hip/hip_bf16.h>
#include <stdint.h>

#define Bdim 8
#define Nseq 1024
#define Cdim 768
#define Hn 12
#define HD 64
#define EPSf 1e-6f

typedef __bf16 bf16;
typedef __bf16 bf16x8 __attribute__((ext_vector_type(8)));
typedef float f32x4 __attribute__((ext_vector_type(4)));

static __device__ __forceinline__ void gload_lds16(const bf16* g, bf16* lds) {
  __builtin_amdgcn_global_load_lds(
      (const __attribute__((address_space(1))) uint32_t*)g,
      (__attribute__((address_space(3))) uint32_t*)lds, 16, 0, 0);
}

// ---------------- fp32 -> bf16 convert (8 elems/thread, sizes are multiples of 2048)
__global__ __launch_bounds__(256) void cvt_f32_bf16(const float* __restrict__ src,
                                                    bf16* __restrict__ dst, int n) {
  const int i = (blockIdx.x * 256 + threadIdx.x) * 8;
  if (i >= n) return;
  float4 a = *(const float4*)(src + i);
  float4 b = *(const float4*)(src + i + 4);
  bf16x8 o;
  o[0] = (bf16)a.x; o[1] = (bf16)a.y; o[2] = (bf16)a.z; o[3] = (bf16)a.w;
  o[4] = (bf16)b.x; o[5] = (bf16)b.y; o[6] = (bf16)b.z; o[7] = (bf16)b.w;
  *(bf16x8*)(dst + i) = o;
}

// ---------------- QKV GEMM: X(8192x768) @ Wqkv^T(768x2304) -> Qs (pre-scaled), K, Vt
__global__ __launch_bounds__(256) void gemm_qkv(
    const bf16* __restrict__ X, const bf16* __restrict__ W,
    bf16* __restrict__ Qb, bf16* __restrict__ Kb, bf16* __restrict__ Vt) {
  __shared__ __align__(16) bf16 As[128 * 32];
  __shared__ __align__(16) bf16 Bs[128 * 32];
  const int t = threadIdx.x;
  const int lane = t & 63;
  const int w = t >> 6;
  const int l15 = lane & 15, quad = lane >> 4;
  const int wm = w & 1, wn = w >> 1;
  const int mbase = blockIdx.y * 128;
  const int nbase = blockIdx.x * 128;
  constexpr int K = Cdim;

  const int srow = t >> 2;
  const int scol = (t & 3) * 8;
  const bf16* Ag = X + (size_t)(mbase + srow) * K + scol;
  const bf16* Bg = W + (size_t)(nbase + srow) * K + scol;
  bf16* AsT = As + t * 8;
  bf16* BsT = Bs + t * 8;

  f32x4 acc[4][4] = {};

  for (int kt = 0; kt < K; kt += 32) {
    gload_lds16(Ag + kt, AsT);
    gload_lds16(Ag + (size_t)64 * K + kt, AsT + 2048);
    gload_lds16(Bg + kt, BsT);
    gload_lds16(Bg + (size_t)64 * K + kt, BsT + 2048);
    __syncthreads();
    bf16x8 a[4], b[4];
#pragma unroll
    for (int mt = 0; mt < 4; mt++)
      a[mt] = *(const bf16x8*)(As + (wm * 64 + mt * 16 + l15) * 32 + quad * 8);
#pragma unroll
    for (int nt = 0; nt < 4; nt++)
      b[nt] = *(const bf16x8*)(Bs + (wn * 64 + nt * 16 + l15) * 32 + quad * 8);
#pragma unroll
    for (int mt = 0; mt < 4; mt++)
#pragma unroll
      for (int nt = 0; nt < 4; nt++)
        acc[mt][nt] = __builtin_amdgcn_mfma_f32_16x16x32_bf16(a[mt], b[nt], acc[mt][nt], 0, 0, 0);
    __syncthreads();
  }

  const int s = nbase / Cdim;  // uniform per block (768 % 128 == 0)
  const float oscale = (s == 0) ? 0.125f : 1.0f;  // fold hd^-0.5 into Q
  const int jbase = (nbase % Cdim) + wn * 64;
#pragma unroll
  for (int nt = 0; nt < 4; nt++) {
    const int jj = jbase + nt * 16 + l15;
    const int h = jj >> 6, d = jj & 63;
#pragma unroll
    for (int mt = 0; mt < 4; mt++) {
#pragma unroll
      for (int r = 0; r < 4; r++) {
        const int m = mbase + wm * 64 + mt * 16 + quad * 4 + r;
        const int b_ = m >> 10, n = m & 1023;
        const bf16 v = (bf16)(acc[mt][nt][r] * oscale);
        const size_t bh = (size_t)b_ * Hn + h;
        if (s == 0)      Qb[(bh * Nseq + n) * HD + d] = v;
        else if (s == 1) Kb[(bh * Nseq + n) * HD + d] = v;
        else             Vt[(bh * HD + d) * Nseq + n] = v;  // transposed V
      }
    }
  }
}

// ---------------- column sums of V per (b,h,d): one wave per Vt row
__global__ __launch_bounds__(256) void colsum_v(const bf16* __restrict__ Vt,
                                                float* __restrict__ CS) {
  const int row = blockIdx.x * 4 + (threadIdx.x >> 6);
  const int lane = threadIdx.x & 63;
  const bf16x8* p = (const bf16x8*)(Vt + (size_t)row * Nseq + lane * 16);
  bf16x8 v0 = p[0], v1 = p[1];
  float s = 0.f;
#pragma unroll
  for (int i = 0; i < 8; i++) s += (float)v0[i] + (float)v1[i];
#pragma unroll
  for (int off = 1; off < 64; off <<= 1) s += __shfl_xor(s, off);
  if (lane == 0) CS[row] = s;
}

// ---------------- fused flash attention with policy softmax
// 4 waves/block; 32 queries/wave (128/block); 64-key tiles LDS-staged, shared by waves.
// Block swizzle keeps all 8 q-tile blocks of one head on one XCD for L2 K/V reuse.
__global__ __launch_bounds__(256) void attn_fused(
    const bf16* __restrict__ Qb, const bf16* __restrict__ Kb, const bf16* __restrict__ Vt,
    const float* __restrict__ pol, const float* __restrict__ CS, bf16* __restrict__ O) {
  __shared__ __align__(16) bf16 Ks[64 * 64];
  __shared__ __align__(16) bf16 Vs[64 * 64];
  __shared__ __align__(16) bf16 Pbuf[4][32 * 40];  // 32q x 32k, row stride 40
  const int t = threadIdx.x, w = t >> 6, lane = t & 63;
  const int l15 = lane & 15, quad = lane >> 4;

  // swizzle: head g -> XCD g%8 (assumes round-robin blockIdx->XCD; perf-only)
  const int bx = blockIdx.x;
  const int g = (bx & 7) + 8 * (bx >> 6);  // head 0..95
  const int qt = (bx >> 3) & 7;            // q-tile 0..7
  const int b_ = g / Hn, h = g % Hn;
  const int qbase = qt * 128 + w * 32;

  const bf16* Qp = Qb + (size_t)g * Nseq * HD;
  const bf16* Kp = Kb + (size_t)g * Nseq * HD;
  const bf16* Vp = Vt + (size_t)g * HD * Nseq;
  const float* polb = pol + (size_t)b_ * Nseq;

  // staging chunk mapping with XOR-16B segment swizzle (choose SOURCE per lane)
  const int ci0 = t, ci1 = t + 256;
  const int row0 = ci0 >> 3, seg0 = (ci0 & 7) ^ (row0 & 7);
  const int row1 = ci1 >> 3, seg1 = (ci1 & 7) ^ (row1 & 7);

  // Q fragments (A-layout), pre-scaled by 0.125 in gemm_qkv
  bf16x8 aq[2][2];
#pragma unroll
  for (int u = 0; u < 2; u++) {
    aq[u][0] = *(const bf16x8*)(Qp + (qbase + u * 16 + l15) * HD + quad * 8);
    aq[u][1] = *(const bf16x8*)(Qp + (qbase + u * 16 + l15) * HD + 32 + quad * 8);
  }

  float polq[2][4];
#pragma unroll
  for (int u = 0; u < 2; u++)
#pragma unroll
    for (int r = 0; r < 4; r++) polq[u][r] = polb[qbase + u * 16 + quad * 4 + r];

  float mrow[2][4], lrow[2][4];
  f32x4 oacc[2][4] = {};
#pragma unroll
  for (int u = 0; u < 2; u++)
#pragma unroll
    for (int r = 0; r < 4; r++) { mrow[u][r] = -1e30f; lrow[u][r] = 0.f; }

  bf16* Pw = &Pbuf[w][0];
  const int swA = (quad ^ (l15 & 7)) * 8;        // k-half 0 swizzled seg offset
  const int swB = ((quad ^ 4) ^ (l15 & 7)) * 8;  // k-half 1

  for (int kt = 0; kt < Nseq; kt += 64) {
    __syncthreads();  // prior tile's LDS reads done
    gload_lds16(Kp + (kt + row0) * HD + seg0 * 8, Ks + ci0 * 8);
    gload_lds16(Kp + (kt + row1) * HD + seg1 * 8, Ks + ci1 * 8);
    gload_lds16(Vp + (size_t)row0 * Nseq + kt + seg0 * 8, Vs + ci0 * 8);
    gload_lds16(Vp + (size_t)row1 * Nseq + kt + seg1 * 8, Vs + ci1 * 8);
    __syncthreads();  // staging complete (vmcnt drained by barrier semantics)

    // ---- QK^T: S[u][s] over 64 keys
    f32x4 S[2][4] = {};
#pragma unroll
    for (int s = 0; s < 4; s++) {
      const int i = s * 16 + l15;
      bf16x8 bk0 = *(const bf16x8*)(Ks + i * 64 + swA);
      bf16x8 bk1 = *(const bf16x8*)(Ks + i * 64 + swB);
#pragma unroll
      for (int u = 0; u < 2; u++) {
        S[u][s] = __builtin_amdgcn_mfma_f32_16x16x32_bf16(aq[u][0], bk0, S[u][s], 0, 0, 0);
        S[u][s] = __builtin_amdgcn_mfma_f32_16x16x32_bf16(aq[u][1], bk1, S[u][s], 0, 0, 0);
      }
    }

    float polk[4];
#pragma unroll
    for (int s = 0; s < 4; s++) polk[s] = polb[kt + s * 16 + l15];

    // ---- online softmax update over the 64-key tile; p overwrites S
#pragma unroll
    for (int u = 0; u < 2; u++)
#pragma unroll
      for (int r = 0; r < 4; r++) {
        float v = fmaxf(fmaxf(S[u][0][r], S[u][1][r]), fmaxf(S[u][2][r], S[u][3][r]));
        v = fmaxf(v, __shfl_xor(v, 1));
        v = fmaxf(v, __shfl_xor(v, 2));
        v = fmaxf(v, __shfl_xor(v, 4));
        v = fmaxf(v, __shfl_xor(v, 8));
        const float mnew = fmaxf(mrow[u][r], v);
        const float alpha = __expf(mrow[u][r] - mnew);
        mrow[u][r] = mnew;
        const int q = qbase + u * 16 + quad * 4 + r;
        float psum = 0.f;
#pragma unroll
        for (int s = 0; s < 4; s++) {
          const int kidx = kt + s * 16 + l15;
          const float msk = polk[s] * polq[u][r] + (1.f - polk[s]) * ((q == kidx) ? 1.f : 0.f);
          const float p = __expf(S[u][s][r] - mnew) * msk;
          S[u][s][r] = p;
          psum += p;
        }
        lrow[u][r] = lrow[u][r] * alpha + psum;
#pragma unroll
        for (int c = 0; c < 4; c++) oacc[u][c][r] *= alpha;
      }

    // ---- PV in two 32-key halves through per-wave P buffer
#pragma unroll
    for (int hh = 0; hh < 2; hh++) {
#pragma unroll
      for (int u = 0; u < 2; u++)
#pragma unroll
        for (int sl = 0; sl < 2; sl++)
#pragma unroll
          for (int r = 0; r < 4; r++)
            Pw[(u * 16 + quad * 4 + r) * 40 + sl * 16 + l15] = (bf16)S[u][hh * 2 + sl][r];
      asm volatile("s_waitcnt lgkmcnt(0)" ::: "memory");
      bf16x8 ap[2];
#pragma unroll
      for (int u = 0; u < 2; u++)
        ap[u] = *(const bf16x8*)(Pw + (u * 16 + l15) * 40 + quad * 8);
      const int swV = (((hh * 4 + quad)) ^ (l15 & 7)) * 8;
#pragma unroll
      for (int c = 0; c < 4; c++) {
        const int i = c * 16 + l15;
        bf16x8 bv = *(const bf16x8*)(Vs + i * 64 + swV);
#pragma unroll
        for (int u = 0; u < 2; u++)
          oacc[u][c] = __builtin_amdgcn_mfma_f32_16x16x32_bf16(ap[u], bv, oacc[u][c], 0, 0, 0);
      }
    }
  }

  // ---- epilogue: reduce l, add eps terms, write O
#pragma unroll
  for (int u = 0; u < 2; u++)
#pragma unroll
    for (int r = 0; r < 4; r++) {
      float v = lrow[u][r];
      v += __shfl_xor(v, 1);
      v += __shfl_xor(v, 2);
      v += __shfl_xor(v, 4);
      v += __shfl_xor(v, 8);
      lrow[u][r] = v + EPSf;
    }
  const float epsN = EPSf / (float)Nseq;
  const float* CSp = CS + (size_t)g * HD;
#pragma unroll
  for (int c = 0; c < 4; c++) {
    const float cs = CSp[c * 16 + l15] * epsN;
#pragma unroll
    for (int u = 0; u < 2; u++)
#pragma unroll
      for (int r = 0; r < 4; r++) {
        const int q = qbase + u * 16 + quad * 4 + r;
        const float val = (oacc[u][c][r] + cs) / lrow[u][r];
        O[((size_t)b_ * Nseq + q) * Cdim + h * 64 + c * 16 + l15] = (bf16)val;
      }
  }
}

// ---------------- proj GEMM: O(8192x768) @ Wproj^T(768x768) + bias -> out (fp32)
__global__ __launch_bounds__(256) void gemm_proj(
    const bf16* __restrict__ A_, const bf16* __restrict__ W,
    const float* __restrict__ bias, float* __restrict__ out) {
  __shared__ __align__(16) bf16 As[128 * 32];
  __shared__ __align__(16) bf16 Bs[128 * 32];
  const int t = threadIdx.x;
  const int lane = t & 63;
  const int w = t >> 6;
  const int l15 = lane & 15, quad = lane >> 4;
  const int wm = w & 1, wn = w >> 1;
  const int mbase = blockIdx.y * 128;
  const int nbase = blockIdx.x * 128;
  constexpr int K = Cdim;

  const int srow = t >> 2;
  const int scol = (t & 3) * 8;
  const bf16* Ag = A_ + (size_t)(mbase + srow) * K + scol;
  const bf16* Bg = W + (size_t)(nbase + srow) * K + scol;
  bf16* AsT = As + t * 8;
  bf16* BsT = Bs + t * 8;

  f32x4 acc[4][4] = {};

  for (int kt = 0; kt < K; kt += 32) {
    gload_lds16(Ag + kt, AsT);
    gload_lds16(Ag + (size_t)64 * K + kt, AsT + 2048);
    gload_lds16(Bg + kt, BsT);
    gload_lds16(Bg + (size_t)64 * K + kt, BsT + 2048);
    __syncthreads();
    bf16x8 a[4], b[4];
#pragma unroll
    for (int mt = 0; mt < 4; mt++)
      a[mt] = *(const bf16x8*)(As + (wm * 64 + mt * 16 + l15) * 32 + quad * 8);
#pragma unroll
    for (int nt = 0; nt < 4; nt++)
      b[nt] = *(const bf16x8*)(Bs + (wn * 64 + nt * 16 + l15) * 32 + quad * 8);
#pragma unroll
    for (int mt = 0; mt < 4; mt++)
#pragma unroll
      for (int nt = 0; nt < 4; nt++)
        acc[mt][nt] = __builtin_amdgcn_mfma_f32_16x16x32_bf16(a[mt], b[nt], acc[mt][nt], 0, 0, 0);
    __syncthreads();
  }

#pragma unroll
  for (int nt = 0; nt < 4; nt++) {
    const int j = nbase + wn * 64 + nt * 16 + l15;
    const float bj = bias[j];
#pragma unroll
    for (int mt = 0; mt < 4; mt++)
#pragma unroll
      for (int r = 0; r < 4; r++) {
        const int m = mbase + wm * 64 + mt * 16 + quad * 4 + r;
        out[(size_t)m * Cdim + j] = acc[mt][nt][r] + bj;
      }
  }
}

extern "C" void kernel_launch(void* const* d_in, const int* in_sizes, int n_in,
                              void* d_out, int out_size, void* d_ws, size_t ws_size,
                              hipStream_t stream) {
  const float* x = (const float*)d_in[0];
  const float* pol = (const float*)d_in[1];
  const float* Wqkv = (const float*)d_in[2];
  const float* Wproj = (const float*)d_in[3];
  const float* bproj = (const float*)d_in[4];
  float* out = (float*)d_out;
  char* ws = (char*)d_ws;

  const size_t SZ = (size_t)Bdim * Hn * Nseq * HD * sizeof(bf16);  // 12.58 MB
  bf16* Qb = (bf16*)(ws);
  bf16* Kb = (bf16*)(ws + SZ);
  bf16* Vt = (bf16*)(ws + 2 * SZ);
  bf16* O  = (bf16*)(ws + 3 * SZ);
  float* CS = (float*)(ws + 4 * SZ);            // B*H*HD fp32 (24 KB)
  bf16* Xb = (bf16*)(ws + 4 * SZ + 32 * 1024);  // 12.58 MB
  bf16* Wqkvb = Xb + (size_t)Bdim * Nseq * Cdim;   // 3.54 MB
  bf16* Wprojb = Wqkvb + (size_t)3 * Cdim * Cdim;  // 1.18 MB

  const int nx = Bdim * Nseq * Cdim;
  const int nwq = 3 * Cdim * Cdim;
  const int nwp = Cdim * Cdim;
  cvt_f32_bf16<<<nx / 2048, 256, 0, stream>>>(x, Xb, nx);
  cvt_f32_bf16<<<nwq / 2048, 256, 0, stream>>>(Wqkv, Wqkvb, nwq);
  cvt_f32_bf16<<<nwp / 2048, 256, 0, stream>>>(Wproj, Wprojb, nwp);

  gemm_qkv<<<dim3(3 * Cdim / 128, (Bdim * Nseq) / 128), 256, 0, stream>>>(Xb, Wqkvb, Qb, Kb, Vt);
  colsum_v<<<(Bdim * Hn * HD) / 4, 256, 0, stream>>>(Vt, CS);
  attn_fused<<<Bdim * Hn * (Nseq / 128), 256, 0, stream>>>(Qb, Kb, Vt, pol, CS, O);
  gemm_proj<<<dim3(Cdim / 128, (Bdim * Nseq) / 128), 256, 0, stream>>>(O, Wprojb, bproj, out);
}

// Round 4
// 240.772 us; speedup vs baseline: 1.5807x; 1.1010x over previous
//
#include <hip/hip_runtime.h>
#include <hip/hip_bf16.h>
#include <stdint.h>

#define Bdim 8
#define Nseq 1024
#define Cdim 768
#define Hn 12
#define HD 64
#define EPSf 1e-6f

typedef __bf16 bf16;
typedef __bf16 bf16x8 __attribute__((ext_vector_type(8)));
typedef float f32x4 __attribute__((ext_vector_type(4)));

static __device__ __forceinline__ void gload_lds16(const bf16* g, bf16* lds) {
  __builtin_amdgcn_global_load_lds(
      (const __attribute__((address_space(1))) uint32_t*)g,
      (__attribute__((address_space(3))) uint32_t*)lds, 16, 0, 0);
}

// ---------------- fused fp32 -> bf16 convert for x, Wqkv, Wproj (one launch)
#define NX (Bdim * Nseq * Cdim)
#define NWQ (3 * Cdim * Cdim)
#define NWP (Cdim * Cdim)
__global__ __launch_bounds__(256) void cvt_all(
    const float* __restrict__ x, const float* __restrict__ wq, const float* __restrict__ wp,
    bf16* __restrict__ Xb, bf16* __restrict__ Wqb, bf16* __restrict__ Wpb) {
  const int i = (blockIdx.x * 256 + threadIdx.x) * 8;
  const float* src;
  bf16* dst;
  int off;
  if (i < NX) { src = x; dst = Xb; off = i; }
  else if (i < NX + NWQ) { src = wq; dst = Wqb; off = i - NX; }
  else { src = wp; dst = Wpb; off = i - NX - NWQ; }
  float4 a = *(const float4*)(src + off);
  float4 b = *(const float4*)(src + off + 4);
  bf16x8 o;
  o[0] = (bf16)a.x; o[1] = (bf16)a.y; o[2] = (bf16)a.z; o[3] = (bf16)a.w;
  o[4] = (bf16)b.x; o[5] = (bf16)b.y; o[6] = (bf16)b.z; o[7] = (bf16)b.w;
  *(bf16x8*)(dst + off) = o;
}

// ---------------- QKV GEMM: X(8192x768) @ Wqkv^T(768x2304) -> Qs (pre-scaled), K, Vt
__global__ __launch_bounds__(256) void gemm_qkv(
    const bf16* __restrict__ X, const bf16* __restrict__ W,
    bf16* __restrict__ Qb, bf16* __restrict__ Kb, bf16* __restrict__ Vt) {
  __shared__ __align__(16) bf16 As[128 * 32];
  __shared__ __align__(16) bf16 Bs[128 * 32];
  const int t = threadIdx.x;
  const int lane = t & 63;
  const int w = t >> 6;
  const int l15 = lane & 15, quad = lane >> 4;
  const int wm = w & 1, wn = w >> 1;
  const int mbase = blockIdx.y * 128;
  const int nbase = blockIdx.x * 128;
  constexpr int K = Cdim;

  const int srow = t >> 2;
  const int scol = (t & 3) * 8;
  const bf16* Ag = X + (size_t)(mbase + srow) * K + scol;
  const bf16* Bg = W + (size_t)(nbase + srow) * K + scol;
  bf16* AsT = As + t * 8;
  bf16* BsT = Bs + t * 8;

  f32x4 acc[4][4] = {};

  for (int kt = 0; kt < K; kt += 32) {
    gload_lds16(Ag + kt, AsT);
    gload_lds16(Ag + (size_t)64 * K + kt, AsT + 2048);
    gload_lds16(Bg + kt, BsT);
    gload_lds16(Bg + (size_t)64 * K + kt, BsT + 2048);
    __syncthreads();
    bf16x8 a[4], b[4];
#pragma unroll
    for (int mt = 0; mt < 4; mt++)
      a[mt] = *(const bf16x8*)(As + (wm * 64 + mt * 16 + l15) * 32 + quad * 8);
#pragma unroll
    for (int nt = 0; nt < 4; nt++)
      b[nt] = *(const bf16x8*)(Bs + (wn * 64 + nt * 16 + l15) * 32 + quad * 8);
#pragma unroll
    for (int mt = 0; mt < 4; mt++)
#pragma unroll
      for (int nt = 0; nt < 4; nt++)
        acc[mt][nt] = __builtin_amdgcn_mfma_f32_16x16x32_bf16(a[mt], b[nt], acc[mt][nt], 0, 0, 0);
    __syncthreads();
  }

  const int s = nbase / Cdim;  // uniform per block (768 % 128 == 0)
  const float oscale = (s == 0) ? 0.125f : 1.0f;  // fold hd^-0.5 into Q
  const int jbase = (nbase % Cdim) + wn * 64;
#pragma unroll
  for (int nt = 0; nt < 4; nt++) {
    const int jj = jbase + nt * 16 + l15;
    const int h = jj >> 6, d = jj & 63;
#pragma unroll
    for (int mt = 0; mt < 4; mt++) {
#pragma unroll
      for (int r = 0; r < 4; r++) {
        const int m = mbase + wm * 64 + mt * 16 + quad * 4 + r;
        const int b_ = m >> 10, n = m & 1023;
        const bf16 v = (bf16)(acc[mt][nt][r] * oscale);
        const size_t bh = (size_t)b_ * Hn + h;
        if (s == 0)      Qb[(bh * Nseq + n) * HD + d] = v;
        else if (s == 1) Kb[(bh * Nseq + n) * HD + d] = v;
        else             Vt[(bh * HD + d) * Nseq + n] = v;  // transposed V
      }
    }
  }
}

// ---------------- column sums of V per (b,h,d): one wave per Vt row
__global__ __launch_bounds__(256) void colsum_v(const bf16* __restrict__ Vt,
                                                float* __restrict__ CS) {
  const int row = blockIdx.x * 4 + (threadIdx.x >> 6);
  const int lane = threadIdx.x & 63;
  const bf16x8* p = (const bf16x8*)(Vt + (size_t)row * Nseq + lane * 16);
  bf16x8 v0 = p[0], v1 = p[1];
  float s = 0.f;
#pragma unroll
  for (int i = 0; i < 8; i++) s += (float)v0[i] + (float)v1[i];
#pragma unroll
  for (int off = 1; off < 64; off <<= 1) s += __shfl_xor(s, off);
  if (lane == 0) CS[row] = s;
}

// ---------------- deferred-max softmax update
// mask = polk*polq except diagonal (k==q) where mask==1 exactly (pol in {0,1}).
template <bool DIAG>
static __device__ __forceinline__ void smax_update(
    f32x4 (&S)[2][4], float (&mx)[2][4], float (&lrow)[2][4],
    const float (&polq)[2][4], const float (&polk)[4],
    int kt, int qbase, int quad, int l15) {
#pragma unroll
  for (int u = 0; u < 2; u++)
#pragma unroll
    for (int r = 0; r < 4; r++) {
      const float pm = polq[u][r];
      const float m4 = fmaxf(fmaxf(S[u][0][r], S[u][1][r]), fmaxf(S[u][2][r], S[u][3][r]));
      mx[u][r] = fmaxf(mx[u][r], m4);
      const int q = qbase + u * 16 + quad * 4 + r;
      float psum = 0.f;
#pragma unroll
      for (int s = 0; s < 4; s++) {
        const float e = __expf(S[u][s][r]);
        float p = e * (polk[s] * pm);
        if (DIAG) p = (q == kt + s * 16 + l15) ? e : p;
        S[u][s][r] = p;
        psum += p;
      }
      lrow[u][r] += psum;
    }
}

// ---------------- fused flash attention with policy softmax (deferred max)
__global__ __launch_bounds__(256) void attn_fused(
    const bf16* __restrict__ Qb, const bf16* __restrict__ Kb, const bf16* __restrict__ Vt,
    const float* __restrict__ pol, const float* __restrict__ CS, bf16* __restrict__ O) {
  __shared__ __align__(16) bf16 Ks[64 * 64];
  __shared__ __align__(16) bf16 Vs[64 * 64];
  __shared__ __align__(16) bf16 Pbuf[4][32 * 40];
  __shared__ float Ps[Nseq];  // policy row for this batch
  const int t = threadIdx.x, w = t >> 6, lane = t & 63;
  const int l15 = lane & 15, quad = lane >> 4;

  // swizzle: head g -> XCD g%8 (perf-only heuristic)
  const int bx = blockIdx.x;
  const int g = (bx & 7) + 8 * (bx >> 6);  // head 0..95
  const int qt = (bx >> 3) & 7;            // q-tile 0..7
  const int b_ = g / Hn, h = g % Hn;
  const int qbase = qt * 128 + w * 32;
  const int ktdiag = qbase & ~63;

  const bf16* Qp = Qb + (size_t)g * Nseq * HD;
  const bf16* Kp = Kb + (size_t)g * Nseq * HD;
  const bf16* Vp = Vt + (size_t)g * HD * Nseq;
  const float* polb = pol + (size_t)b_ * Nseq;

  // stage policy row into LDS (covered by first loop barrier)
  *(float4*)(Ps + t * 4) = *(const float4*)(polb + t * 4);

  // staging chunk mapping with XOR-16B segment swizzle (choose SOURCE per lane)
  const int ci0 = t, ci1 = t + 256;
  const int row0 = ci0 >> 3, seg0 = (ci0 & 7) ^ (row0 & 7);
  const int row1 = ci1 >> 3, seg1 = (ci1 & 7) ^ (row1 & 7);

  // Q fragments (A-layout), pre-scaled by 0.125 in gemm_qkv
  bf16x8 aq[2][2];
#pragma unroll
  for (int u = 0; u < 2; u++) {
    aq[u][0] = *(const bf16x8*)(Qp + (qbase + u * 16 + l15) * HD + quad * 8);
    aq[u][1] = *(const bf16x8*)(Qp + (qbase + u * 16 + l15) * HD + 32 + quad * 8);
  }

  float polq[2][4];
#pragma unroll
  for (int u = 0; u < 2; u++)
#pragma unroll
    for (int r = 0; r < 4; r++) polq[u][r] = polb[qbase + u * 16 + quad * 4 + r];

  float mx[2][4], lrow[2][4];
  f32x4 oacc[2][4] = {};
#pragma unroll
  for (int u = 0; u < 2; u++)
#pragma unroll
    for (int r = 0; r < 4; r++) { mx[u][r] = -1e30f; lrow[u][r] = 0.f; }

  bf16* Pw = &Pbuf[w][0];
  const int swA = (quad ^ (l15 & 7)) * 8;
  const int swB = ((quad ^ 4) ^ (l15 & 7)) * 8;

  for (int kt = 0; kt < Nseq; kt += 64) {
    __syncthreads();  // prior tile's LDS reads done (also covers Ps staging)
    gload_lds16(Kp + (kt + row0) * HD + seg0 * 8, Ks + ci0 * 8);
    gload_lds16(Kp + (kt + row1) * HD + seg1 * 8, Ks + ci1 * 8);
    gload_lds16(Vp + (size_t)row0 * Nseq + kt + seg0 * 8, Vs + ci0 * 8);
    gload_lds16(Vp + (size_t)row1 * Nseq + kt + seg1 * 8, Vs + ci1 * 8);
    __syncthreads();  // staging complete

    // ---- QK^T: S[u][s] over 64 keys
    f32x4 S[2][4] = {};
#pragma unroll
    for (int s = 0; s < 4; s++) {
      const int i = s * 16 + l15;
      bf16x8 bk0 = *(const bf16x8*)(Ks + i * 64 + swA);
      bf16x8 bk1 = *(const bf16x8*)(Ks + i * 64 + swB);
#pragma unroll
      for (int u = 0; u < 2; u++) {
        S[u][s] = __builtin_amdgcn_mfma_f32_16x16x32_bf16(aq[u][0], bk0, S[u][s], 0, 0, 0);
        S[u][s] = __builtin_amdgcn_mfma_f32_16x16x32_bf16(aq[u][1], bk1, S[u][s], 0, 0, 0);
      }
    }

    float polk[4];
#pragma unroll
    for (int s = 0; s < 4; s++) polk[s] = Ps[kt + s * 16 + l15];

    // ---- deferred-max softmax: p = exp(s)*mask, raw-max tracked per lane
    if (kt == ktdiag)
      smax_update<true>(S, mx, lrow, polq, polk, kt, qbase, quad, l15);
    else
      smax_update<false>(S, mx, lrow, polq, polk, kt, qbase, quad, l15);

    // ---- PV in two 32-key halves through per-wave P buffer
#pragma unroll
    for (int hh = 0; hh < 2; hh++) {
#pragma unroll
      for (int u = 0; u < 2; u++)
#pragma unroll
        for (int sl = 0; sl < 2; sl++)
#pragma unroll
          for (int r = 0; r < 4; r++)
            Pw[(u * 16 + quad * 4 + r) * 40 + sl * 16 + l15] = (bf16)S[u][hh * 2 + sl][r];
      asm volatile("s_waitcnt lgkmcnt(0)" ::: "memory");
      bf16x8 ap[2];
#pragma unroll
      for (int u = 0; u < 2; u++)
        ap[u] = *(const bf16x8*)(Pw + (u * 16 + l15) * 40 + quad * 8);
      const int swV = (((hh * 4 + quad)) ^ (l15 & 7)) * 8;
#pragma unroll
      for (int c = 0; c < 4; c++) {
        const int i = c * 16 + l15;
        bf16x8 bv = *(const bf16x8*)(Vs + i * 64 + swV);
#pragma unroll
        for (int u = 0; u < 2; u++)
          oacc[u][c] = __builtin_amdgcn_mfma_f32_16x16x32_bf16(ap[u], bv, oacc[u][c], 0, 0, 0);
      }
    }
  }

  // ---- epilogue: reduce l and m, eps correction with e^m, write O
  float rden[2][4], eterm[2][4];
  const float epsN = EPSf / (float)Nseq;
#pragma unroll
  for (int u = 0; u < 2; u++)
#pragma unroll
    for (int r = 0; r < 4; r++) {
      float v = lrow[u][r];
      v += __shfl_xor(v, 1);
      v += __shfl_xor(v, 2);
      v += __shfl_xor(v, 4);
      v += __shfl_xor(v, 8);
      float m = mx[u][r];
      m = fmaxf(m, __shfl_xor(m, 1));
      m = fmaxf(m, __shfl_xor(m, 2));
      m = fmaxf(m, __shfl_xor(m, 4));
      m = fmaxf(m, __shfl_xor(m, 8));
      const float em = __expf(m);
      rden[u][r] = 1.f / (v + EPSf * em);
      eterm[u][r] = epsN * em;
    }
  const float* CSp = CS + (size_t)g * HD;
#pragma unroll
  for (int c = 0; c < 4; c++) {
    const float cs = CSp[c * 16 + l15];
#pragma unroll
    for (int u = 0; u < 2; u++)
#pragma unroll
      for (int r = 0; r < 4; r++) {
        const int q = qbase + u * 16 + quad * 4 + r;
        const float val = (oacc[u][c][r] + cs * eterm[u][r]) * rden[u][r];
        O[((size_t)b_ * Nseq + q) * Cdim + h * 64 + c * 16 + l15] = (bf16)val;
      }
  }
}

// ---------------- proj GEMM: O(8192x768) @ Wproj^T(768x768) + bias -> out (fp32)
__global__ __launch_bounds__(256) void gemm_proj(
    const bf16* __restrict__ A_, const bf16* __restrict__ W,
    const float* __restrict__ bias, float* __restrict__ out) {
  __shared__ __align__(16) bf16 As[128 * 32];
  __shared__ __align__(16) bf16 Bs[128 * 32];
  const int t = threadIdx.x;
  const int lane = t & 63;
  const int w = t >> 6;
  const int l15 = lane & 15, quad = lane >> 4;
  const int wm = w & 1, wn = w >> 1;
  const int mbase = blockIdx.y * 128;
  const int nbase = blockIdx.x * 128;
  constexpr int K = Cdim;

  const int srow = t >> 2;
  const int scol = (t & 3) * 8;
  const bf16* Ag = A_ + (size_t)(mbase + srow) * K + scol;
  const bf16* Bg = W + (size_t)(nbase + srow) * K + scol;
  bf16* AsT = As + t * 8;
  bf16* BsT = Bs + t * 8;

  f32x4 acc[4][4] = {};

  for (int kt = 0; kt < K; kt += 32) {
    gload_lds16(Ag + kt, AsT);
    gload_lds16(Ag + (size_t)64 * K + kt, AsT + 2048);
    gload_lds16(Bg + kt, BsT);
    gload_lds16(Bg + (size_t)64 * K + kt, BsT + 2048);
    __syncthreads();
    bf16x8 a[4], b[4];
#pragma unroll
    for (int mt = 0; mt < 4; mt++)
      a[mt] = *(const bf16x8*)(As + (wm * 64 + mt * 16 + l15) * 32 + quad * 8);
#pragma unroll
    for (int nt = 0; nt < 4; nt++)
      b[nt] = *(const bf16x8*)(Bs + (wn * 64 + nt * 16 + l15) * 32 + quad * 8);
#pragma unroll
    for (int mt = 0; mt < 4; mt++)
#pragma unroll
      for (int nt = 0; nt < 4; nt++)
        acc[mt][nt] = __builtin_amdgcn_mfma_f32_16x16x32_bf16(a[mt], b[nt], acc[mt][nt], 0, 0, 0);
    __syncthreads();
  }

#pragma unroll
  for (int nt = 0; nt < 4; nt++) {
    const int j = nbase + wn * 64 + nt * 16 + l15;
    const float bj = bias[j];
#pragma unroll
    for (int mt = 0; mt < 4; mt++)
#pragma unroll
      for (int r = 0; r < 4; r++) {
        const int m = mbase + wm * 64 + mt * 16 + quad * 4 + r;
        out[(size_t)m * Cdim + j] = acc[mt][nt][r] + bj;
      }
  }
}

extern "C" void kernel_launch(void* const* d_in, const int* in_sizes, int n_in,
                              void* d_out, int out_size, void* d_ws, size_t ws_size,
                              hipStream_t stream) {
  const float* x = (const float*)d_in[0];
  const float* pol = (const float*)d_in[1];
  const float* Wqkv = (const float*)d_in[2];
  const float* Wproj = (const float*)d_in[3];
  const float* bproj = (const float*)d_in[4];
  float* out = (float*)d_out;
  char* ws = (char*)d_ws;

  const size_t SZ = (size_t)Bdim * Hn * Nseq * HD * sizeof(bf16);  // 12.58 MB
  bf16* Qb = (bf16*)(ws);
  bf16* Kb = (bf16*)(ws + SZ);
  bf16* Vt = (bf16*)(ws + 2 * SZ);
  bf16* O  = (bf16*)(ws + 3 * SZ);
  float* CS = (float*)(ws + 4 * SZ);            // B*H*HD fp32 (24 KB)
  bf16* Xb = (bf16*)(ws + 4 * SZ + 32 * 1024);  // 12.58 MB
  bf16* Wqkvb = Xb + (size_t)Bdim * Nseq * Cdim;   // 3.54 MB
  bf16* Wprojb = Wqkvb + (size_t)3 * Cdim * Cdim;  // 1.18 MB

  cvt_all<<<(NX + NWQ + NWP) / 2048, 256, 0, stream>>>(x, Wqkv, Wproj, Xb, Wqkvb, Wprojb);

  gemm_qkv<<<dim3(3 * Cdim / 128, (Bdim * Nseq) / 128), 256, 0, stream>>>(Xb, Wqkvb, Qb, Kb, Vt);
  colsum_v<<<(Bdim * Hn * HD) / 4, 256, 0, stream>>>(Vt, CS);
  attn_fused<<<Bdim * Hn * (Nseq / 128), 256, 0, stream>>>(Qb, Kb, Vt, pol, CS, O);
  gemm_proj<<<dim3(Cdim / 128, (Bdim * Nseq) / 128), 256, 0, stream>>>(O, Wprojb, bproj, out);
}

// Round 5
// 221.848 us; speedup vs baseline: 1.7155x; 1.0853x over previous
//
#include <hip/hip_runtime.h>
#include <hip/hip_bf16.h>
#include <stdint.h>

#define Bdim 8
#define Nseq 1024
#define Cdim 768
#define Hn 12
#define HD 64
#define EPSf 1e-6f

typedef __bf16 bf16;
typedef __bf16 bf16x8 __attribute__((ext_vector_type(8)));
typedef float f32x4 __attribute__((ext_vector_type(4)));

static __device__ __forceinline__ void gload_lds16(const bf16* g, bf16* lds) {
  __builtin_amdgcn_global_load_lds(
      (const __attribute__((address_space(1))) uint32_t*)g,
      (__attribute__((address_space(3))) uint32_t*)lds, 16, 0, 0);
}

// ---------------- fused fp32 -> bf16 convert for x, Wqkv, Wproj; also zeroes CS
#define NX (Bdim * Nseq * Cdim)
#define NWQ (3 * Cdim * Cdim)
#define NWP (Cdim * Cdim)
__global__ __launch_bounds__(256) void cvt_all(
    const float* __restrict__ x, const float* __restrict__ wq, const float* __restrict__ wp,
    bf16* __restrict__ Xb, bf16* __restrict__ Wqb, bf16* __restrict__ Wpb,
    float* __restrict__ CS) {
  if (blockIdx.x < 24) CS[blockIdx.x * 256 + threadIdx.x] = 0.f;  // 96*64 floats
  const int i = (blockIdx.x * 256 + threadIdx.x) * 8;
  const float* src;
  bf16* dst;
  int off;
  if (i < NX) { src = x; dst = Xb; off = i; }
  else if (i < NX + NWQ) { src = wq; dst = Wqb; off = i - NX; }
  else { src = wp; dst = Wpb; off = i - NX - NWQ; }
  float4 a = *(const float4*)(src + off);
  float4 b = *(const float4*)(src + off + 4);
  bf16x8 o;
  o[0] = (bf16)a.x; o[1] = (bf16)a.y; o[2] = (bf16)a.z; o[3] = (bf16)a.w;
  o[4] = (bf16)b.x; o[5] = (bf16)b.y; o[6] = (bf16)b.z; o[7] = (bf16)b.w;
  *(bf16x8*)(dst + off) = o;
}

// ---------------- QKV GEMM: 128x128 tile, BK=64, XCD-striped, fused V colsum
// X(8192x768) @ Wqkv^T -> Qs (pre-scaled), K (B,H,N,hd), Vt (B,H,hd,N), CS (+=)
__global__ __launch_bounds__(256) void gemm_qkv(
    const bf16* __restrict__ X, const bf16* __restrict__ W,
    bf16* __restrict__ Qb, bf16* __restrict__ Kb, bf16* __restrict__ Vt,
    float* __restrict__ CS) {
  __shared__ __align__(16) bf16 As[128 * 64];  // 16 KB, row stride 64, XOR-16B swizzled
  __shared__ __align__(16) bf16 Bs[128 * 64];
  const int t = threadIdx.x;
  const int lane = t & 63;
  const int w = t >> 6;
  const int l15 = lane & 15, quad = lane >> 4;
  const int wm = w & 1, wn = w >> 1;
  constexpr int K = Cdim;

  // XCD stripe: flat&7 -> XCD; 8 consecutive m-tiles per XCD, nx sweeps inside
  const int flat = blockIdx.y * 18 + blockIdx.x;  // grid (18, 64)
  const int xcd = flat & 7, idx = flat >> 3;      // idx 0..143
  const int my = (idx & 7) + xcd * 8;             // 0..63
  const int nx = idx >> 3;                        // 0..17
  const int mbase = my * 128;
  const int nbase = nx * 128;

  // staging: chunk ci = call*256 + t; row = ci>>3; slot = ci&7; src seg = slot^(row&7)
  const int srow = t >> 3, slot = t & 7;
  f32x4 acc[4][4] = {};

  for (int kt = 0; kt < K; kt += 64) {
#pragma unroll
    for (int j = 0; j < 4; j++) {
      const int row = j * 32 + srow;
      const int seg = slot ^ (row & 7);
      gload_lds16(X + (size_t)(mbase + row) * K + kt + seg * 8, As + (j * 256 + t) * 8);
    }
#pragma unroll
    for (int j = 0; j < 4; j++) {
      const int row = j * 32 + srow;
      const int seg = slot ^ (row & 7);
      gload_lds16(W + (size_t)(nbase + row) * K + kt + seg * 8, Bs + (j * 256 + t) * 8);
    }
    __syncthreads();
#pragma unroll
    for (int kh = 0; kh < 2; kh++) {
      bf16x8 a[4], b[4];
#pragma unroll
      for (int mt = 0; mt < 4; mt++) {
        const int row = wm * 64 + mt * 16 + l15;
        a[mt] = *(const bf16x8*)(As + row * 64 + ((kh * 4 + quad) ^ (row & 7)) * 8);
      }
#pragma unroll
      for (int nt = 0; nt < 4; nt++) {
        const int row = wn * 64 + nt * 16 + l15;
        b[nt] = *(const bf16x8*)(Bs + row * 64 + ((kh * 4 + quad) ^ (row & 7)) * 8);
      }
#pragma unroll
      for (int mt = 0; mt < 4; mt++)
#pragma unroll
        for (int nt = 0; nt < 4; nt++)
          acc[mt][nt] = __builtin_amdgcn_mfma_f32_16x16x32_bf16(a[mt], b[nt], acc[mt][nt], 0, 0, 0);
    }
    __syncthreads();
  }

  const int s = nbase / Cdim;  // uniform per block
  const float oscale = (s == 0) ? 0.125f : 1.0f;
  const int jbase = (nbase % Cdim) + wn * 64;
  const int b0 = mbase >> 10;
#pragma unroll
  for (int nt = 0; nt < 4; nt++) {
    const int jj = jbase + nt * 16 + l15;
    const int h = jj >> 6, d = jj & 63;
#pragma unroll
    for (int mt = 0; mt < 4; mt++) {
#pragma unroll
      for (int r = 0; r < 4; r++) {
        const int m = mbase + wm * 64 + mt * 16 + quad * 4 + r;
        const int n = m & 1023;
        const bf16 v = (bf16)(acc[mt][nt][r] * oscale);
        const size_t bh = (size_t)b0 * Hn + h;
        if (s == 0)      Qb[(bh * Nseq + n) * HD + d] = v;
        else if (s == 1) Kb[(bh * Nseq + n) * HD + d] = v;
        else             Vt[(bh * HD + d) * Nseq + n] = v;
      }
    }
  }
  if (s == 2) {  // fused V column-sum partials
#pragma unroll
    for (int nt = 0; nt < 4; nt++) {
      float v = 0.f;
#pragma unroll
      for (int mt = 0; mt < 4; mt++)
#pragma unroll
        for (int r = 0; r < 4; r++) v += acc[mt][nt][r];
      v += __shfl_xor(v, 16);
      v += __shfl_xor(v, 32);
      if (quad == 0) {
        const int jj = jbase + nt * 16 + l15;
        atomicAdd(&CS[((size_t)b0 * Hn + (jj >> 6)) * HD + (jj & 63)], v);
      }
    }
  }
}

// ---------------- deferred-max softmax update
template <bool DIAG>
static __device__ __forceinline__ void smax_update(
    f32x4 (&S)[2][4], float (&mx)[2][4], float (&lrow)[2][4],
    const float (&polq)[2][4], const float (&polk)[4],
    int kt, int qbase, int quad, int l15) {
#pragma unroll
  for (int u = 0; u < 2; u++)
#pragma unroll
    for (int r = 0; r < 4; r++) {
      const float pm = polq[u][r];
      const float m4 = fmaxf(fmaxf(S[u][0][r], S[u][1][r]), fmaxf(S[u][2][r], S[u][3][r]));
      mx[u][r] = fmaxf(mx[u][r], m4);
      const int q = qbase + u * 16 + quad * 4 + r;
      float psum = 0.f;
#pragma unroll
      for (int s = 0; s < 4; s++) {
        const float e = __expf(S[u][s][r]);
        float p = e * (polk[s] * pm);
        if (DIAG) p = (q == kt + s * 16 + l15) ? e : p;
        S[u][s][r] = p;
        psum += p;
      }
      lrow[u][r] += psum;
    }
}

// ---------------- fused flash attention with policy softmax (deferred max)
__global__ __launch_bounds__(256) void attn_fused(
    const bf16* __restrict__ Qb, const bf16* __restrict__ Kb, const bf16* __restrict__ Vt,
    const float* __restrict__ pol, const float* __restrict__ CS, bf16* __restrict__ O) {
  __shared__ __align__(16) bf16 Ks[64 * 64];
  __shared__ __align__(16) bf16 Vs[64 * 64];
  __shared__ __align__(16) bf16 Pbuf[4][32 * 40];
  __shared__ float Ps[Nseq];
  const int t = threadIdx.x, w = t >> 6, lane = t & 63;
  const int l15 = lane & 15, quad = lane >> 4;

  const int bx = blockIdx.x;
  const int g = (bx & 7) + 8 * (bx >> 6);  // head 0..95 -> XCD g%8
  const int qt = (bx >> 3) & 7;
  const int b_ = g / Hn, h = g % Hn;
  const int qbase = qt * 128 + w * 32;
  const int ktdiag = qbase & ~63;

  const bf16* Qp = Qb + (size_t)g * Nseq * HD;
  const bf16* Kp = Kb + (size_t)g * Nseq * HD;
  const bf16* Vp = Vt + (size_t)g * HD * Nseq;
  const float* polb = pol + (size_t)b_ * Nseq;

  *(float4*)(Ps + t * 4) = *(const float4*)(polb + t * 4);

  const int ci0 = t, ci1 = t + 256;
  const int row0 = ci0 >> 3, seg0 = (ci0 & 7) ^ (row0 & 7);
  const int row1 = ci1 >> 3, seg1 = (ci1 & 7) ^ (row1 & 7);

  bf16x8 aq[2][2];
#pragma unroll
  for (int u = 0; u < 2; u++) {
    aq[u][0] = *(const bf16x8*)(Qp + (qbase + u * 16 + l15) * HD + quad * 8);
    aq[u][1] = *(const bf16x8*)(Qp + (qbase + u * 16 + l15) * HD + 32 + quad * 8);
  }

  float polq[2][4];
#pragma unroll
  for (int u = 0; u < 2; u++)
#pragma unroll
    for (int r = 0; r < 4; r++) polq[u][r] = polb[qbase + u * 16 + quad * 4 + r];

  float mx[2][4], lrow[2][4];
  f32x4 oacc[2][4] = {};
#pragma unroll
  for (int u = 0; u < 2; u++)
#pragma unroll
    for (int r = 0; r < 4; r++) { mx[u][r] = -1e30f; lrow[u][r] = 0.f; }

  bf16* Pw = &Pbuf[w][0];
  const int swA = (quad ^ (l15 & 7)) * 8;
  const int swB = ((quad ^ 4) ^ (l15 & 7)) * 8;

  for (int kt = 0; kt < Nseq; kt += 64) {
    __syncthreads();
    gload_lds16(Kp + (kt + row0) * HD + seg0 * 8, Ks + ci0 * 8);
    gload_lds16(Kp + (kt + row1) * HD + seg1 * 8, Ks + ci1 * 8);
    gload_lds16(Vp + (size_t)row0 * Nseq + kt + seg0 * 8, Vs + ci0 * 8);
    gload_lds16(Vp + (size_t)row1 * Nseq + kt + seg1 * 8, Vs + ci1 * 8);
    __syncthreads();

    f32x4 S[2][4] = {};
#pragma unroll
    for (int s = 0; s < 4; s++) {
      const int i = s * 16 + l15;
      bf16x8 bk0 = *(const bf16x8*)(Ks + i * 64 + swA);
      bf16x8 bk1 = *(const bf16x8*)(Ks + i * 64 + swB);
#pragma unroll
      for (int u = 0; u < 2; u++) {
        S[u][s] = __builtin_amdgcn_mfma_f32_16x16x32_bf16(aq[u][0], bk0, S[u][s], 0, 0, 0);
        S[u][s] = __builtin_amdgcn_mfma_f32_16x16x32_bf16(aq[u][1], bk1, S[u][s], 0, 0, 0);
      }
    }

    float polk[4];
#pragma unroll
    for (int s = 0; s < 4; s++) polk[s] = Ps[kt + s * 16 + l15];

    if (kt == ktdiag)
      smax_update<true>(S, mx, lrow, polq, polk, kt, qbase, quad, l15);
    else
      smax_update<false>(S, mx, lrow, polq, polk, kt, qbase, quad, l15);

#pragma unroll
    for (int hh = 0; hh < 2; hh++) {
#pragma unroll
      for (int u = 0; u < 2; u++)
#pragma unroll
        for (int sl = 0; sl < 2; sl++)
#pragma unroll
          for (int r = 0; r < 4; r++)
            Pw[(u * 16 + quad * 4 + r) * 40 + sl * 16 + l15] = (bf16)S[u][hh * 2 + sl][r];
      asm volatile("s_waitcnt lgkmcnt(0)" ::: "memory");
      bf16x8 ap[2];
#pragma unroll
      for (int u = 0; u < 2; u++)
        ap[u] = *(const bf16x8*)(Pw + (u * 16 + l15) * 40 + quad * 8);
      const int swV = (((hh * 4 + quad)) ^ (l15 & 7)) * 8;
#pragma unroll
      for (int c = 0; c < 4; c++) {
        const int i = c * 16 + l15;
        bf16x8 bv = *(const bf16x8*)(Vs + i * 64 + swV);
#pragma unroll
        for (int u = 0; u < 2; u++)
          oacc[u][c] = __builtin_amdgcn_mfma_f32_16x16x32_bf16(ap[u], bv, oacc[u][c], 0, 0, 0);
      }
    }
  }

  float rden[2][4], eterm[2][4];
  const float epsN = EPSf / (float)Nseq;
#pragma unroll
  for (int u = 0; u < 2; u++)
#pragma unroll
    for (int r = 0; r < 4; r++) {
      float v = lrow[u][r];
      v += __shfl_xor(v, 1);
      v += __shfl_xor(v, 2);
      v += __shfl_xor(v, 4);
      v += __shfl_xor(v, 8);
      float m = mx[u][r];
      m = fmaxf(m, __shfl_xor(m, 1));
      m = fmaxf(m, __shfl_xor(m, 2));
      m = fmaxf(m, __shfl_xor(m, 4));
      m = fmaxf(m, __shfl_xor(m, 8));
      const float em = __expf(m);
      rden[u][r] = 1.f / (v + EPSf * em);
      eterm[u][r] = epsN * em;
    }
  const float* CSp = CS + (size_t)g * HD;
#pragma unroll
  for (int c = 0; c < 4; c++) {
    const float cs = CSp[c * 16 + l15];
#pragma unroll
    for (int u = 0; u < 2; u++)
#pragma unroll
      for (int r = 0; r < 4; r++) {
        const int q = qbase + u * 16 + quad * 4 + r;
        const float val = (oacc[u][c][r] + cs * eterm[u][r]) * rden[u][r];
        O[((size_t)b_ * Nseq + q) * Cdim + h * 64 + c * 16 + l15] = (bf16)val;
      }
  }
}

// ---------------- proj GEMM: 64x128 tile, BK=64, XCD-striped
// O(8192x768) @ Wproj^T(768x768) + bias -> out (fp32)
__global__ __launch_bounds__(256) void gemm_proj(
    const bf16* __restrict__ A_, const bf16* __restrict__ W,
    const float* __restrict__ bias, float* __restrict__ out) {
  __shared__ __align__(16) bf16 As[64 * 64];   // 8 KB
  __shared__ __align__(16) bf16 Bs[128 * 64];  // 16 KB
  const int t = threadIdx.x;
  const int lane = t & 63;
  const int wn = t >> 6;  // wave = n-quarter
  const int l15 = lane & 15, quad = lane >> 4;
  constexpr int K = Cdim;

  const int flat = blockIdx.y * 6 + blockIdx.x;  // grid (6, 128) = 768 blocks
  const int xcd = flat & 7, idx = flat >> 3;     // idx 0..95
  const int my = (idx & 15) + xcd * 16;          // 0..127
  const int nx = idx >> 4;                       // 0..5
  const int mbase = my * 64;
  const int nbase = nx * 128;

  const int srow = t >> 3, slot = t & 7;
  f32x4 acc[4][2] = {};

  for (int kt = 0; kt < K; kt += 64) {
#pragma unroll
    for (int j = 0; j < 2; j++) {
      const int row = j * 32 + srow;
      const int seg = slot ^ (row & 7);
      gload_lds16(A_ + (size_t)(mbase + row) * K + kt + seg * 8, As + (j * 256 + t) * 8);
    }
#pragma unroll
    for (int j = 0; j < 4; j++) {
      const int row = j * 32 + srow;
      const int seg = slot ^ (row & 7);
      gload_lds16(W + (size_t)(nbase + row) * K + kt + seg * 8, Bs + (j * 256 + t) * 8);
    }
    __syncthreads();
#pragma unroll
    for (int kh = 0; kh < 2; kh++) {
      bf16x8 a[4], b[2];
#pragma unroll
      for (int mt = 0; mt < 4; mt++) {
        const int row = mt * 16 + l15;
        a[mt] = *(const bf16x8*)(As + row * 64 + ((kh * 4 + quad) ^ (row & 7)) * 8);
      }
#pragma unroll
      for (int nt = 0; nt < 2; nt++) {
        const int row = wn * 32 + nt * 16 + l15;
        b[nt] = *(const bf16x8*)(Bs + row * 64 + ((kh * 4 + quad) ^ (row & 7)) * 8);
      }
#pragma unroll
      for (int mt = 0; mt < 4; mt++)
#pragma unroll
        for (int nt = 0; nt < 2; nt++)
          acc[mt][nt] = __builtin_amdgcn_mfma_f32_16x16x32_bf16(a[mt], b[nt], acc[mt][nt], 0, 0, 0);
    }
    __syncthreads();
  }

#pragma unroll
  for (int nt = 0; nt < 2; nt++) {
    const int j = nbase + wn * 32 + nt * 16 + l15;
    const float bj = bias[j];
#pragma unroll
    for (int mt = 0; mt < 4; mt++)
#pragma unroll
      for (int r = 0; r < 4; r++) {
        const int m = mbase + mt * 16 + quad * 4 + r;
        out[(size_t)m * Cdim + j] = acc[mt][nt][r] + bj;
      }
  }
}

extern "C" void kernel_launch(void* const* d_in, const int* in_sizes, int n_in,
                              void* d_out, int out_size, void* d_ws, size_t ws_size,
                              hipStream_t stream) {
  const float* x = (const float*)d_in[0];
  const float* pol = (const float*)d_in[1];
  const float* Wqkv = (const float*)d_in[2];
  const float* Wproj = (const float*)d_in[3];
  const float* bproj = (const float*)d_in[4];
  float* out = (float*)d_out;
  char* ws = (char*)d_ws;

  const size_t SZ = (size_t)Bdim * Hn * Nseq * HD * sizeof(bf16);  // 12.58 MB
  bf16* Qb = (bf16*)(ws);
  bf16* Kb = (bf16*)(ws + SZ);
  bf16* Vt = (bf16*)(ws + 2 * SZ);
  bf16* O  = (bf16*)(ws + 3 * SZ);
  float* CS = (float*)(ws + 4 * SZ);            // 96*64 fp32 (24 KB)
  bf16* Xb = (bf16*)(ws + 4 * SZ + 32 * 1024);
  bf16* Wqkvb = Xb + (size_t)Bdim * Nseq * Cdim;
  bf16* Wprojb = Wqkvb + (size_t)3 * Cdim * Cdim;

  cvt_all<<<(NX + NWQ + NWP) / 2048, 256, 0, stream>>>(x, Wqkv, Wproj, Xb, Wqkvb, Wprojb, CS);
  gemm_qkv<<<dim3(18, 64), 256, 0, stream>>>(Xb, Wqkvb, Qb, Kb, Vt, CS);
  attn_fused<<<Bdim * Hn * (Nseq / 128), 256, 0, stream>>>(Qb, Kb, Vt, pol, CS, O);
  gemm_proj<<<dim3(6, 128), 256, 0, stream>>>(O, Wprojb, bproj, out);
}

// Round 6
// 212.501 us; speedup vs baseline: 1.7910x; 1.0440x over previous
//
#include <hip/hip_runtime.h>
#include <hip/hip_bf16.h>
#include <stdint.h>

#define Bdim 8
#define Nseq 1024
#define Cdim 768
#define Hn 12
#define HD 64
#define EPSf 1e-6f

typedef __bf16 bf16;
typedef __bf16 bf16x8 __attribute__((ext_vector_type(8)));
typedef float f32x4 __attribute__((ext_vector_type(4)));

static __device__ __forceinline__ void gload_lds16(const bf16* g, bf16* lds) {
  __builtin_amdgcn_global_load_lds(
      (const __attribute__((address_space(1))) uint32_t*)g,
      (__attribute__((address_space(3))) uint32_t*)lds, 16, 0, 0);
}

// ---------------- fused fp32 -> bf16 convert for x, Wqkv, Wproj; also zeroes CS
#define NX (Bdim * Nseq * Cdim)
#define NWQ (3 * Cdim * Cdim)
#define NWP (Cdim * Cdim)
__global__ __launch_bounds__(256) void cvt_all(
    const float* __restrict__ x, const float* __restrict__ wq, const float* __restrict__ wp,
    bf16* __restrict__ Xb, bf16* __restrict__ Wqb, bf16* __restrict__ Wpb,
    float* __restrict__ CS) {
  if (blockIdx.x < 24) CS[blockIdx.x * 256 + threadIdx.x] = 0.f;  // 96*64 floats
  const int i = (blockIdx.x * 256 + threadIdx.x) * 8;
  const float* src;
  bf16* dst;
  int off;
  if (i < NX) { src = x; dst = Xb; off = i; }
  else if (i < NX + NWQ) { src = wq; dst = Wqb; off = i - NX; }
  else { src = wp; dst = Wpb; off = i - NX - NWQ; }
  float4 a = *(const float4*)(src + off);
  float4 b = *(const float4*)(src + off + 4);
  bf16x8 o;
  o[0] = (bf16)a.x; o[1] = (bf16)a.y; o[2] = (bf16)a.z; o[3] = (bf16)a.w;
  o[4] = (bf16)b.x; o[5] = (bf16)b.y; o[6] = (bf16)b.z; o[7] = (bf16)b.w;
  *(bf16x8*)(dst + off) = o;
}

// ---------------- QKV GEMM: 128x128 tile, BK=64, XCD-striped, fused V colsum
// Vt stored KEY-INTERLEAVED within each 32-key group: pos32 = quad*8 + g16*4 + r
// so attention PV B-fragments are contiguous 16B.
__global__ __launch_bounds__(256) void gemm_qkv(
    const bf16* __restrict__ X, const bf16* __restrict__ W,
    bf16* __restrict__ Qb, bf16* __restrict__ Kb, bf16* __restrict__ Vt,
    float* __restrict__ CS) {
  __shared__ __align__(16) bf16 As[128 * 64];
  __shared__ __align__(16) bf16 Bs[128 * 64];
  const int t = threadIdx.x;
  const int lane = t & 63;
  const int w = t >> 6;
  const int l15 = lane & 15, quad = lane >> 4;
  const int wm = w & 1, wn = w >> 1;
  constexpr int K = Cdim;

  const int flat = blockIdx.y * 18 + blockIdx.x;  // grid (18, 64)
  const int xcd = flat & 7, idx = flat >> 3;
  const int my = (idx & 7) + xcd * 8;
  const int nx = idx >> 3;
  const int mbase = my * 128;
  const int nbase = nx * 128;

  const int srow = t >> 3, slot = t & 7;
  f32x4 acc[4][4] = {};

  for (int kt = 0; kt < K; kt += 64) {
#pragma unroll
    for (int j = 0; j < 4; j++) {
      const int row = j * 32 + srow;
      const int seg = slot ^ (row & 7);
      gload_lds16(X + (size_t)(mbase + row) * K + kt + seg * 8, As + (j * 256 + t) * 8);
    }
#pragma unroll
    for (int j = 0; j < 4; j++) {
      const int row = j * 32 + srow;
      const int seg = slot ^ (row & 7);
      gload_lds16(W + (size_t)(nbase + row) * K + kt + seg * 8, Bs + (j * 256 + t) * 8);
    }
    __syncthreads();
#pragma unroll
    for (int kh = 0; kh < 2; kh++) {
      bf16x8 a[4], b[4];
#pragma unroll
      for (int mt = 0; mt < 4; mt++) {
        const int row = wm * 64 + mt * 16 + l15;
        a[mt] = *(const bf16x8*)(As + row * 64 + ((kh * 4 + quad) ^ (row & 7)) * 8);
      }
#pragma unroll
      for (int nt = 0; nt < 4; nt++) {
        const int row = wn * 64 + nt * 16 + l15;
        b[nt] = *(const bf16x8*)(Bs + row * 64 + ((kh * 4 + quad) ^ (row & 7)) * 8);
      }
#pragma unroll
      for (int mt = 0; mt < 4; mt++)
#pragma unroll
        for (int nt = 0; nt < 4; nt++)
          acc[mt][nt] = __builtin_amdgcn_mfma_f32_16x16x32_bf16(a[mt], b[nt], acc[mt][nt], 0, 0, 0);
    }
    __syncthreads();
  }

  const int s = nbase / Cdim;
  const float oscale = (s == 0) ? 0.125f : 1.0f;
  const int jbase = (nbase % Cdim) + wn * 64;
  const int b0 = mbase >> 10;
#pragma unroll
  for (int nt = 0; nt < 4; nt++) {
    const int jj = jbase + nt * 16 + l15;
    const int h = jj >> 6, d = jj & 63;
#pragma unroll
    for (int mt = 0; mt < 4; mt++) {
#pragma unroll
      for (int r = 0; r < 4; r++) {
        const int m = mbase + wm * 64 + mt * 16 + quad * 4 + r;
        const int n = m & 1023;
        const bf16 v = (bf16)(acc[mt][nt][r] * oscale);
        const size_t bh = (size_t)b0 * Hn + h;
        if (s == 0)      Qb[(bh * Nseq + n) * HD + d] = v;
        else if (s == 1) Kb[(bh * Nseq + n) * HD + d] = v;
        else {
          const int nperm = (n & ~31) | (quad * 8 + (mt & 1) * 4 + r);
          Vt[(bh * HD + d) * Nseq + nperm] = v;
        }
      }
    }
  }
  if (s == 2) {  // fused V column-sum partials (permutation-invariant)
#pragma unroll
    for (int nt = 0; nt < 4; nt++) {
      float v = 0.f;
#pragma unroll
      for (int mt = 0; mt < 4; mt++)
#pragma unroll
        for (int r = 0; r < 4; r++) v += acc[mt][nt][r];
      v += __shfl_xor(v, 16);
      v += __shfl_xor(v, 32);
      if (quad == 0) {
        const int jj = jbase + nt * 16 + l15;
        atomicAdd(&CS[((size_t)b0 * Hn + (jj >> 6)) * HD + (jj & 63)], v);
      }
    }
  }
}

// ---------------- deferred-max softmax update on S^T tiles
// S[u][kg][r] = score(query=qbase+u*16+l15, key=kt+kg*16+quad*4+r)
template <bool DIAG>
static __device__ __forceinline__ void smax_update(
    f32x4 (&S)[2][4], float (&mx)[2], float (&lrow)[2],
    const float (&polq)[2], const float4 (&pk)[4],
    int kt, int qbase, int quad, int l15) {
#pragma unroll
  for (int u = 0; u < 2; u++) {
    const float pm = polq[u];
    const int q = qbase + u * 16 + l15;
    float m4 = -1e30f, psum = 0.f;
#pragma unroll
    for (int kg = 0; kg < 4; kg++)
#pragma unroll
      for (int r = 0; r < 4; r++) m4 = fmaxf(m4, S[u][kg][r]);
    mx[u] = fmaxf(mx[u], m4);
#pragma unroll
    for (int kg = 0; kg < 4; kg++) {
      const float* pkk = (const float*)&pk[kg];
#pragma unroll
      for (int r = 0; r < 4; r++) {
        const float e = __expf(S[u][kg][r]);
        float p = e * (pkk[r] * pm);
        if (DIAG) p = (q == kt + kg * 16 + quad * 4 + r) ? e : p;
        S[u][kg][r] = p;
        psum += p;
      }
    }
    lrow[u] += psum;
  }
}

// ---------------- fused flash attention, S^T form, double-buffered K/V staging
__global__ __launch_bounds__(256) void attn_fused(
    const bf16* __restrict__ Qb, const bf16* __restrict__ Kb, const bf16* __restrict__ Vt,
    const float* __restrict__ pol, const float* __restrict__ CS, bf16* __restrict__ O) {
  __shared__ __align__(16) bf16 Ks[2][64 * 64];
  __shared__ __align__(16) bf16 Vs[2][64 * 64];
  __shared__ float Ps[Nseq];
  const int t = threadIdx.x, w = t >> 6, lane = t & 63;
  const int l15 = lane & 15, quad = lane >> 4;

  const int bx = blockIdx.x;
  const int g = (bx & 7) + 8 * (bx >> 6);  // head 0..95 -> XCD g%8
  const int qt = (bx >> 3) & 7;
  const int b_ = g / Hn, h = g % Hn;
  const int qbase = qt * 128 + w * 32;
  const int ktdiag = qbase & ~63;

  const bf16* Qp = Qb + (size_t)g * Nseq * HD;
  const bf16* Kp = Kb + (size_t)g * Nseq * HD;
  const bf16* Vp = Vt + (size_t)g * HD * Nseq;
  const float* polb = pol + (size_t)b_ * Nseq;

  *(float4*)(Ps + t * 4) = *(const float4*)(polb + t * 4);

  const int ci0 = t, ci1 = t + 256;
  const int row0 = ci0 >> 3, seg0 = (ci0 & 7) ^ (row0 & 7);
  const int row1 = ci1 >> 3, seg1 = (ci1 & 7) ^ (row1 & 7);

  // Q fragments (used as B-operand): B[n=query=l15][k=d=quad*8+j]
  bf16x8 aq[2][2];
#pragma unroll
  for (int u = 0; u < 2; u++) {
    aq[u][0] = *(const bf16x8*)(Qp + (qbase + u * 16 + l15) * HD + quad * 8);
    aq[u][1] = *(const bf16x8*)(Qp + (qbase + u * 16 + l15) * HD + 32 + quad * 8);
  }
  float polq[2] = { polb[qbase + l15], polb[qbase + 16 + l15] };

  float mx[2] = { -1e30f, -1e30f }, lrow[2] = { 0.f, 0.f };
  f32x4 oacc[2][4] = {};

  // prologue: stage tile 0 into buffer 0
  gload_lds16(Kp + row0 * HD + seg0 * 8, &Ks[0][ci0 * 8]);
  gload_lds16(Kp + row1 * HD + seg1 * 8, &Ks[0][ci1 * 8]);
  gload_lds16(Vp + (size_t)row0 * Nseq + seg0 * 8, &Vs[0][ci0 * 8]);
  gload_lds16(Vp + (size_t)row1 * Nseq + seg1 * 8, &Vs[0][ci1 * 8]);

  for (int kt = 0; kt < Nseq; kt += 64) {
    const int buf = (kt >> 6) & 1;
    __syncthreads();  // drains this tile's staging; syncs prev compute on other buf
    if (kt + 64 < Nseq) {
      const int nb = buf ^ 1;
      gload_lds16(Kp + (kt + 64 + row0) * HD + seg0 * 8, &Ks[nb][ci0 * 8]);
      gload_lds16(Kp + (kt + 64 + row1) * HD + seg1 * 8, &Ks[nb][ci1 * 8]);
      gload_lds16(Vp + (size_t)row0 * Nseq + kt + 64 + seg0 * 8, &Vs[nb][ci0 * 8]);
      gload_lds16(Vp + (size_t)row1 * Nseq + kt + 64 + seg1 * 8, &Vs[nb][ci1 * 8]);
    }

    // ---- K@Q^T -> S^T: A=K (m=key), B=Q (n=query)
    f32x4 S[2][4] = {};
#pragma unroll
    for (int kg = 0; kg < 4; kg++) {
      const int row = kg * 16 + l15;
      bf16x8 bk0 = *(const bf16x8*)(&Ks[buf][row * 64 + ((quad ^ (row & 7)) * 8)]);
      bf16x8 bk1 = *(const bf16x8*)(&Ks[buf][row * 64 + (((quad ^ 4) ^ (row & 7)) * 8)]);
#pragma unroll
      for (int u = 0; u < 2; u++) {
        S[u][kg] = __builtin_amdgcn_mfma_f32_16x16x32_bf16(bk0, aq[u][0], S[u][kg], 0, 0, 0);
        S[u][kg] = __builtin_amdgcn_mfma_f32_16x16x32_bf16(bk1, aq[u][1], S[u][kg], 0, 0, 0);
      }
    }

    float4 pk[4];
#pragma unroll
    for (int kg = 0; kg < 4; kg++)
      pk[kg] = *(const float4*)(Ps + kt + kg * 16 + quad * 4);

    if (kt == ktdiag)
      smax_update<true>(S, mx, lrow, polq, pk, kt, qbase, quad, l15);
    else
      smax_update<false>(S, mx, lrow, polq, pk, kt, qbase, quad, l15);

    // ---- PV: A=P (already in lane-natural k-permuted A-layout), B=V (interleaved Vt)
#pragma unroll
    for (int hh = 0; hh < 2; hh++) {
      bf16x8 ap[2];
#pragma unroll
      for (int u = 0; u < 2; u++)
#pragma unroll
        for (int j = 0; j < 4; j++) {
          ap[u][j] = (bf16)S[u][2 * hh][j];
          ap[u][4 + j] = (bf16)S[u][2 * hh + 1][j];
        }
#pragma unroll
      for (int c = 0; c < 4; c++) {
        const int row = c * 16 + l15;
        bf16x8 bv = *(const bf16x8*)(&Vs[buf][row * 64 + (((hh * 4 + quad) ^ (row & 7)) * 8)]);
#pragma unroll
        for (int u = 0; u < 2; u++)
          oacc[u][c] = __builtin_amdgcn_mfma_f32_16x16x32_bf16(ap[u], bv, oacc[u][c], 0, 0, 0);
      }
    }
  }

  // ---- epilogue: reduce l,m across quads (lanes sharing l15), redistribute to rows
  const float epsN = EPSf / (float)Nseq;
  float rden[2][4], eterm[2][4];
#pragma unroll
  for (int u = 0; u < 2; u++) {
    float v = lrow[u];
    v += __shfl_xor(v, 16);
    v += __shfl_xor(v, 32);
    float m = mx[u];
    m = fmaxf(m, __shfl_xor(m, 16));
    m = fmaxf(m, __shfl_xor(m, 32));
    const float em = __expf(m);
    const float den = v + EPSf * em;
    const float eN = epsN * em;
    const int base = lane & 48;
#pragma unroll
    for (int r = 0; r < 4; r++) {
      rden[u][r] = 1.f / __shfl(den, base | (quad * 4 + r));
      eterm[u][r] = __shfl(eN, base | (quad * 4 + r));
    }
  }
  const float* CSp = CS + (size_t)g * HD;
#pragma unroll
  for (int c = 0; c < 4; c++) {
    const float cs = CSp[c * 16 + l15];
#pragma unroll
    for (int u = 0; u < 2; u++)
#pragma unroll
      for (int r = 0; r < 4; r++) {
        const int q = qbase + u * 16 + quad * 4 + r;
        const float val = (oacc[u][c][r] + cs * eterm[u][r]) * rden[u][r];
        O[((size_t)b_ * Nseq + q) * Cdim + h * 64 + c * 16 + l15] = (bf16)val;
      }
  }
}

// ---------------- proj GEMM: 64x128 tile, BK=64, XCD-striped
__global__ __launch_bounds__(256) void gemm_proj(
    const bf16* __restrict__ A_, const bf16* __restrict__ W,
    const float* __restrict__ bias, float* __restrict__ out) {
  __shared__ __align__(16) bf16 As[64 * 64];
  __shared__ __align__(16) bf16 Bs[128 * 64];
  const int t = threadIdx.x;
  const int lane = t & 63;
  const int wn = t >> 6;
  const int l15 = lane & 15, quad = lane >> 4;
  constexpr int K = Cdim;

  const int flat = blockIdx.y * 6 + blockIdx.x;  // grid (6, 128)
  const int xcd = flat & 7, idx = flat >> 3;
  const int my = (idx & 15) + xcd * 16;
  const int nx = idx >> 4;
  const int mbase = my * 64;
  const int nbase = nx * 128;

  const int srow = t >> 3, slot = t & 7;
  f32x4 acc[4][2] = {};

  for (int kt = 0; kt < K; kt += 64) {
#pragma unroll
    for (int j = 0; j < 2; j++) {
      const int row = j * 32 + srow;
      const int seg = slot ^ (row & 7);
      gload_lds16(A_ + (size_t)(mbase + row) * K + kt + seg * 8, As + (j * 256 + t) * 8);
    }
#pragma unroll
    for (int j = 0; j < 4; j++) {
      const int row = j * 32 + srow;
      const int seg = slot ^ (row & 7);
      gload_lds16(W + (size_t)(nbase + row) * K + kt + seg * 8, Bs + (j * 256 + t) * 8);
    }
    __syncthreads();
#pragma unroll
    for (int kh = 0; kh < 2; kh++) {
      bf16x8 a[4], b[2];
#pragma unroll
      for (int mt = 0; mt < 4; mt++) {
        const int row = mt * 16 + l15;
        a[mt] = *(const bf16x8*)(As + row * 64 + ((kh * 4 + quad) ^ (row & 7)) * 8);
      }
#pragma unroll
      for (int nt = 0; nt < 2; nt++) {
        const int row = wn * 32 + nt * 16 + l15;
        b[nt] = *(const bf16x8*)(Bs + row * 64 + ((kh * 4 + quad) ^ (row & 7)) * 8);
      }
#pragma unroll
      for (int mt = 0; mt < 4; mt++)
#pragma unroll
        for (int nt = 0; nt < 2; nt++)
          acc[mt][nt] = __builtin_amdgcn_mfma_f32_16x16x32_bf16(a[mt], b[nt], acc[mt][nt], 0, 0, 0);
    }
    __syncthreads();
  }

#pragma unroll
  for (int nt = 0; nt < 2; nt++) {
    const int j = nbase + wn * 32 + nt * 16 + l15;
    const float bj = bias[j];
#pragma unroll
    for (int mt = 0; mt < 4; mt++)
#pragma unroll
      for (int r = 0; r < 4; r++) {
        const int m = mbase + mt * 16 + quad * 4 + r;
        out[(size_t)m * Cdim + j] = acc[mt][nt][r] + bj;
      }
  }
}

extern "C" void kernel_launch(void* const* d_in, const int* in_sizes, int n_in,
                              void* d_out, int out_size, void* d_ws, size_t ws_size,
                              hipStream_t stream) {
  const float* x = (const float*)d_in[0];
  const float* pol = (const float*)d_in[1];
  const float* Wqkv = (const float*)d_in[2];
  const float* Wproj = (const float*)d_in[3];
  const float* bproj = (const float*)d_in[4];
  float* out = (float*)d_out;
  char* ws = (char*)d_ws;

  const size_t SZ = (size_t)Bdim * Hn * Nseq * HD * sizeof(bf16);  // 12.58 MB
  bf16* Qb = (bf16*)(ws);
  bf16* Kb = (bf16*)(ws + SZ);
  bf16* Vt = (bf16*)(ws + 2 * SZ);
  bf16* O  = (bf16*)(ws + 3 * SZ);
  float* CS = (float*)(ws + 4 * SZ);
  bf16* Xb = (bf16*)(ws + 4 * SZ + 32 * 1024);
  bf16* Wqkvb = Xb + (size_t)Bdim * Nseq * Cdim;
  bf16* Wprojb = Wqkvb + (size_t)3 * Cdim * Cdim;

  cvt_all<<<(NX + NWQ + NWP) / 2048, 256, 0, stream>>>(x, Wqkv, Wproj, Xb, Wqkvb, Wprojb, CS);
  gemm_qkv<<<dim3(18, 64), 256, 0, stream>>>(Xb, Wqkvb, Qb, Kb, Vt, CS);
  attn_fused<<<Bdim * Hn * (Nseq / 128), 256, 0, stream>>>(Qb, Kb, Vt, pol, CS, O);
  gemm_proj<<<dim3(6, 128), 256, 0, stream>>>(O, Wprojb, bproj, out);
}